// Round 1
// baseline (14386.436 us; speedup 1.0000x reference)
//
#include <hip/hip_runtime.h>
#include <hip/hip_bf16.h>
#include <cstdint>

// ---------------------------------------------------------------------------
// 2-layer LSTM, SEQ=512 B=64 IN=512 HID=1024.
// Plan: bulk bf16 GEMM for input-gate preactivations (biases folded),
// then 512 per-step kernels per layer for the recurrence (h @ w_hh^T
// computed transposed: gates^T = w_hh @ h^T, w_hh streamed once/step,
// h LDS-staged with XOR swizzle, K split across 4 waves, LDS reduce,
// fused nonlinearity epilogue).
// ---------------------------------------------------------------------------

typedef __attribute__((ext_vector_type(8))) short short8;   // 8 bf16 = 4 VGPR
typedef __attribute__((ext_vector_type(4))) float f32x4;

#define AS1 __attribute__((address_space(1)))
#define AS3 __attribute__((address_space(3)))

static __device__ __forceinline__ void gload_lds16(const void* g, void* l) {
  __builtin_amdgcn_global_load_lds((const AS1 unsigned int*)g, (AS3 unsigned int*)l,
                                   16, 0, 0);
}

static __device__ __forceinline__ float sigmoidf_(float x) {
  return 1.f / (1.f + __expf(-x));
}

// --------------------------- f32 -> bf16 convert ---------------------------
__global__ void cvt_bf16(const float* __restrict__ in, __hip_bfloat16* __restrict__ out,
                         int n4) {
  int i = blockIdx.x * 256 + threadIdx.x;
  if (i >= n4) return;
  float4 v = ((const float4*)in)[i];
  out[i * 4 + 0] = __float2bfloat16(v.x);
  out[i * 4 + 1] = __float2bfloat16(v.y);
  out[i * 4 + 2] = __float2bfloat16(v.z);
  out[i * 4 + 3] = __float2bfloat16(v.w);
}

// ------------------------------ state init --------------------------------
__global__ void init_state(const float* __restrict__ h0, const float* __restrict__ c0,
                           __hip_bfloat16* __restrict__ h_init, float* __restrict__ c_state,
                           int n) {
  int i = blockIdx.x * 256 + threadIdx.x;
  if (i >= n) return;
  h_init[i] = __float2bfloat16(h0[i]);
  c_state[i] = c0[i];
}

// ------------------------------- finalize ---------------------------------
__global__ void finalize_out(const float* __restrict__ hf, const float* __restrict__ cst,
                             float* __restrict__ out_h, float* __restrict__ out_c, int n) {
  int i = blockIdx.x * 256 + threadIdx.x;
  if (i >= n) return;
  out_h[i] = hf[i];
  out_c[i] = cst[i];
}

// --------------------- big GEMM: C = A @ B^T + b1 + b2 ---------------------
// A: [M,K] bf16 row-major, B: [N,K] bf16 row-major, C: [M,N] bf16.
// 128x128 tile, BK=64, 4 waves (2x2 of 64x64), global_load_lds staging.
// M multiple of 128, N multiple of 128, K multiple of 64 (all true here).
__global__ __launch_bounds__(256) void gemm_bt_bias(
    const __hip_bfloat16* __restrict__ A, const __hip_bfloat16* __restrict__ B,
    __hip_bfloat16* __restrict__ C, const float* __restrict__ bias1,
    const float* __restrict__ bias2, int K, int N) {
  const int tid = threadIdx.x;
  const int lane = tid & 63;
  const int wv = tid >> 6;
  const int l15 = lane & 15, l4 = lane >> 4;
  const int bm = blockIdx.x * 128;
  const int bn = blockIdx.y * 128;
  __shared__ alignas(16) __hip_bfloat16 As[128 * 64];
  __shared__ alignas(16) __hip_bfloat16 Bs[128 * 64];
  f32x4 acc[4][4] = {};
  const int wm = (wv >> 1) * 64;
  const int wn = (wv & 1) * 64;

  for (int kt = 0; kt < K; kt += 64) {
    if (kt) __syncthreads();  // previous-iteration LDS reads complete
#pragma unroll
    for (int it = 0; it < 4; ++it) {
      int ci = it * 256 + tid;       // 16B chunk index
      int row = ci >> 3, c8 = ci & 7;
      // LDS dest must be wave-uniform base (+ lane*16 by HW)
      gload_lds16(A + (bm + row) * K + kt + c8 * 8, As + (it * 256 + wv * 64) * 8);
      gload_lds16(B + (bn + row) * K + kt + c8 * 8, Bs + (it * 256 + wv * 64) * 8);
    }
    __syncthreads();
#pragma unroll
    for (int kk = 0; kk < 64; kk += 32) {
      short8 a[4], b[4];
#pragma unroll
      for (int m = 0; m < 4; ++m)
        a[m] = *(const short8*)(As + (wm + m * 16 + l15) * 64 + kk + l4 * 8);
#pragma unroll
      for (int n = 0; n < 4; ++n)
        b[n] = *(const short8*)(Bs + (wn + n * 16 + l15) * 64 + kk + l4 * 8);
#pragma unroll
      for (int m = 0; m < 4; ++m)
#pragma unroll
        for (int n = 0; n < 4; ++n)
          acc[m][n] = __builtin_amdgcn_mfma_f32_16x16x32_bf16(a[m], b[n], acc[m][n], 0, 0, 0);
    }
  }
  // epilogue: + bias, store bf16. D: col = lane&15, row = (lane>>4)*4 + j.
#pragma unroll
  for (int n = 0; n < 4; ++n) {
    int col = bn + wn + n * 16 + l15;
    float bs = bias1[col] + bias2[col];
#pragma unroll
    for (int m = 0; m < 4; ++m) {
#pragma unroll
      for (int j = 0; j < 4; ++j) {
        int row = bm + wm + m * 16 + l4 * 4 + j;
        C[(size_t)row * N + col] = __float2bfloat16(acc[m][n][j] + bs);
      }
    }
  }
}

// ----------------------------- LSTM step kernel -----------------------------
// grid 64 blocks x 256 threads. Block bi owns hidden strip [bi*16, bi*16+16).
// Computes gates^T = w_hh @ h^T for its 64 gate-rows (4 gates x 16 hidden),
// K=1024 split across 4 waves; LDS reduce; fused LSTM cell update.
__global__ __launch_bounds__(256) void lstm_step(
    const __hip_bfloat16* __restrict__ Gin_t,  // [64][4096] input preact (+biases)
    const __hip_bfloat16* __restrict__ Whh,    // [4096][1024] bf16
    const __hip_bfloat16* __restrict__ h_in,   // [64][1024] bf16
    __hip_bfloat16* __restrict__ h_out,        // [64][1024] bf16
    float* __restrict__ c,                     // [64][1024] f32 (in/out)
    float* __restrict__ y_f32,                 // [64][1024] f32 or null
    float* __restrict__ h_f32) {               // [64][1024] f32 or null (final h)
  const int tid = threadIdx.x;
  const int lane = tid & 63;
  const int wv = tid >> 6;  // K-chunk 0..3
  const int l15 = lane & 15, l4 = lane >> 4;
  const int hs0 = blockIdx.x * 16;
  __shared__ alignas(16) unsigned char smem[131072];  // h stage, then reduce buf

  // stage h [64][1024] bf16 -> LDS with XOR swizzle (kills 16-way conflict)
#pragma unroll
  for (int it = 0; it < 32; ++it) {
    int ci = it * 256 + tid;   // 16B chunk
    int row = ci >> 7;         // 1024 bf16 = 128 chunks per row
    float4 v = *(const float4*)((const char*)h_in + (size_t)ci * 16);
    *(float4*)(smem + ((ci * 16) ^ ((row & 7) << 4))) = v;
  }
  __syncthreads();

  f32x4 acc[4][4] = {};  // [gate][batch-frag]
  const __hip_bfloat16* wbase = Whh + (hs0 + l15) * 1024;
#pragma unroll
  for (int ks = 0; ks < 8; ++ks) {
    const int k = wv * 256 + ks * 32 + l4 * 8;
    short8 a[4], b[4];
#pragma unroll
    for (int m = 0; m < 4; ++m)  // gate m rows: m*1024 + hs0 + l15
      a[m] = *(const short8*)(wbase + m * (1024 * 1024) + k);
#pragma unroll
    for (int n = 0; n < 4; ++n) {  // batch rows n*16 + l15 from swizzled LDS
      int row = n * 16 + l15;
      b[n] = *(const short8*)(smem + ((row * 2048 + k * 2) ^ ((row & 7) << 4)));
    }
#pragma unroll
    for (int m = 0; m < 4; ++m)
#pragma unroll
      for (int n = 0; n < 4; ++n)
        acc[m][n] = __builtin_amdgcn_mfma_f32_16x16x32_bf16(a[m], b[n], acc[m][n], 0, 0, 0);
  }
  __syncthreads();  // all h reads done; reuse LDS for K-chunk partials

  // partials: red[wv][gaterow 0..63][batch 0..63] f32 (16 KB per wave)
  float* red = (float*)smem + wv * 4096;
#pragma unroll
  for (int m = 0; m < 4; ++m)
#pragma unroll
    for (int n = 0; n < 4; ++n)
#pragma unroll
      for (int j = 0; j < 4; ++j)
        red[(m * 16 + l4 * 4 + j) * 64 + n * 16 + l15] = acc[m][n][j];
  __syncthreads();

  // final: 1024 (r16, batch) outputs across 256 threads
  const float* r0 = (const float*)smem;
#pragma unroll
  for (int pp = 0; pp < 4; ++pp) {
    int pid = pp * 256 + tid;
    int r16 = pid >> 6, bb = pid & 63;
    float gs[4];
#pragma unroll
    for (int g = 0; g < 4; ++g) {
      int o = (g * 16 + r16) * 64 + bb;
      gs[g] = r0[o] + r0[4096 + o] + r0[8192 + o] + r0[12288 + o] +
              __bfloat162float(Gin_t[bb * 4096 + g * 1024 + hs0 + r16]);
    }
    float ig = sigmoidf_(gs[0]);
    float fg = sigmoidf_(gs[1]);
    float gg = tanhf(gs[2]);
    float og = sigmoidf_(gs[3]);
    int idx = bb * 1024 + hs0 + r16;
    float cn = fg * c[idx] + ig * gg;
    c[idx] = cn;
    float hn = og * tanhf(cn);
    h_out[idx] = __float2bfloat16(hn);
    if (h_f32) h_f32[idx] = hn;
    if (y_f32) y_f32[idx] = hn;
  }
}

// ---------------------------------------------------------------------------
extern "C" void kernel_launch(void* const* d_in, const int* in_sizes, int n_in,
                              void* d_out_, int out_size, void* d_ws, size_t ws_size,
                              hipStream_t stream) {
  (void)in_sizes; (void)n_in; (void)out_size; (void)ws_size;
  const float* x      = (const float*)d_in[0];   // [512,64,512]
  const float* h0     = (const float*)d_in[1];   // [2,64,1024]
  const float* c0     = (const float*)d_in[2];
  const float* w_ih_0 = (const float*)d_in[3];   // [4096,512]
  const float* w_hh_0 = (const float*)d_in[4];   // [4096,1024]
  const float* b_ih_0 = (const float*)d_in[5];
  const float* b_hh_0 = (const float*)d_in[6];
  const float* w_ih_1 = (const float*)d_in[7];   // [4096,1024]
  const float* w_hh_1 = (const float*)d_in[8];
  const float* b_ih_1 = (const float*)d_in[9];
  const float* b_hh_1 = (const float*)d_in[10];
  float* out = (float*)d_out_;

  // workspace carve-up (~382 MB total)
  char* p = (char*)d_ws;
  auto alloc = [&](size_t bytes) { char* r = p; p += (bytes + 255) & ~(size_t)255; return r; };
  __hip_bfloat16* xb    = (__hip_bfloat16*)alloc(33554432);   // x bf16 [32768,512]
  __hip_bfloat16* wbih0 = (__hip_bfloat16*)alloc(4194304);
  __hip_bfloat16* wbhh0 = (__hip_bfloat16*)alloc(8388608);
  __hip_bfloat16* wbih1 = (__hip_bfloat16*)alloc(8388608);
  __hip_bfloat16* wbhh1 = (__hip_bfloat16*)alloc(8388608);
  __hip_bfloat16* y0b   = (__hip_bfloat16*)alloc(67108864);   // layer-0 h history bf16
  __hip_bfloat16* Gin   = (__hip_bfloat16*)alloc(268435456);  // [32768,4096] bf16
  __hip_bfloat16* hinit = (__hip_bfloat16*)alloc(262144);     // [2][64][1024] bf16
  __hip_bfloat16* hbuf0 = (__hip_bfloat16*)alloc(131072);     // layer-1 ping
  __hip_bfloat16* hbuf1 = (__hip_bfloat16*)alloc(131072);     // layer-1 pong
  float* cst            = (float*)alloc(524288);              // [2][64][1024] f32
  float* hf             = (float*)alloc(524288);              // final h f32

  // f32 -> bf16 conversions
  cvt_bf16<<<16777216 / 4 / 256, 256, 0, stream>>>(x, xb, 16777216 / 4);
  cvt_bf16<<<2097152 / 4 / 256, 256, 0, stream>>>(w_ih_0, wbih0, 2097152 / 4);
  cvt_bf16<<<4194304 / 4 / 256, 256, 0, stream>>>(w_hh_0, wbhh0, 4194304 / 4);
  cvt_bf16<<<4194304 / 4 / 256, 256, 0, stream>>>(w_ih_1, wbih1, 4194304 / 4);
  cvt_bf16<<<4194304 / 4 / 256, 256, 0, stream>>>(w_hh_1, wbhh1, 4194304 / 4);
  init_state<<<131072 / 256, 256, 0, stream>>>(h0, c0, hinit, cst, 131072);

  // layer 0 input GEMM: Gin = xb @ w_ih_0^T + b_ih_0 + b_hh_0
  gemm_bt_bias<<<dim3(256, 32), 256, 0, stream>>>(xb, wbih0, Gin, b_ih_0, b_hh_0, 512, 4096);

  // layer 0 recurrence (h history lives in y0b)
  for (int t = 0; t < 512; ++t) {
    const __hip_bfloat16* hi = t ? (y0b + (size_t)(t - 1) * 65536) : hinit;
    lstm_step<<<64, 256, 0, stream>>>(Gin + (size_t)t * 262144, wbhh0, hi,
                                      y0b + (size_t)t * 65536, cst,
                                      nullptr, (t == 511) ? hf : nullptr);
  }

  // layer 1 input GEMM: Gin = y0b @ w_ih_1^T + b_ih_1 + b_hh_1
  gemm_bt_bias<<<dim3(256, 32), 256, 0, stream>>>(y0b, wbih1, Gin, b_ih_1, b_hh_1, 1024, 4096);

  // layer 1 recurrence (y written f32 straight to d_out)
  for (int t = 0; t < 512; ++t) {
    const __hip_bfloat16* hi = t ? ((t & 1) ? hbuf0 : hbuf1) : (hinit + 65536);
    __hip_bfloat16* ho = (t & 1) ? hbuf1 : hbuf0;
    lstm_step<<<64, 256, 0, stream>>>(Gin + (size_t)t * 262144, wbhh1, hi, ho,
                                      cst + 65536, out + (size_t)t * 65536,
                                      (t == 511) ? (hf + 65536) : nullptr);
  }

  // hn, cn tails of d_out
  finalize_out<<<131072 / 256, 256, 0, stream>>>(hf, cst, out + 33554432, out + 33685504, 131072);
}